// Round 3
// baseline (33.457 us; speedup 1.0000x reference)
//
#include <hip/hip_runtime.h>
#include <hip/hip_bf16.h>

using u32 = unsigned int;
using u16 = unsigned short;

typedef __attribute__((ext_vector_type(8))) _Float16 half8;
typedef __attribute__((ext_vector_type(2))) _Float16 half2v;
typedef __attribute__((ext_vector_type(16))) float f32x16;
typedef __attribute__((ext_vector_type(4))) u32 u32x4;

#define IN_K   4096
#define OUT_N  14336
#define SPLITK 8
#define OUT_ELEMS (64 * OUT_N)   // 917504

// ---------------------------------------------------------------------------
// prep: x f32[64][4096] -> xs f16 in MFMA-fragment order.
// xs layout: [512 chunks][64 rows][8 f16]; chunk c covers k = 8c + perm[j],
// perm = {0,4,1,5,2,6,3,7} (matches pair-dequant element order).
__global__ __launch_bounds__(256) void prep_kernel(const float* __restrict__ x,
                                                   u16* __restrict__ xs) {
  const int t = blockIdx.x * 256 + threadIdx.x;   // 32768 threads
  const int c = t >> 6;        // chunk 0..511
  const int r = t & 63;        // row
  const float* px = x + r * IN_K + c * 8;
  const float4 a = *(const float4*)px;
  const float4 b = *(const float4*)(px + 4);
  const float af[4] = {a.x, a.y, a.z, a.w};
  const float bf[4] = {b.x, b.y, b.z, b.w};
  union { u32x4 v; u32 u[4]; } o;
#pragma unroll
  for (int i = 0; i < 4; ++i) {
    const _Float16 hl = (_Float16)af[i];   // k = 8c + i
    const _Float16 hh = (_Float16)bf[i];   // k = 8c + i + 4
    u16 lo, hi;
    __builtin_memcpy(&lo, &hl, 2);
    __builtin_memcpy(&hi, &hh, 2);
    o.u[i] = (u32)lo | ((u32)hi << 16);
  }
  *(u32x4*)(xs + (size_t)t * 8) = o.v;
}

// ---------------------------------------------------------------------------
__global__ __launch_bounds__(256) void bias_init_kernel(const float* __restrict__ bias,
                                                        float* __restrict__ out) {
  const int i = (blockIdx.x * 256 + threadIdx.x) * 4;
  const int col = i % OUT_N;
  *(float4*)(out + i) = *(const float4*)(bias + col);
}

__global__ __launch_bounds__(256) void reduce_kernel(const float* __restrict__ part,
                                                     const float* __restrict__ bias,
                                                     float* __restrict__ out) {
  const int i = (blockIdx.x * 256 + threadIdx.x) * 4;
  const int col = i % OUT_N;
  float4 r = *(const float4*)(bias + col);
#pragma unroll
  for (int p = 0; p < SPLITK; ++p) {
    const float4 a = *(const float4*)(part + (size_t)p * OUT_ELEMS + i);
    r.x += a.x; r.y += a.y; r.z += a.z; r.w += a.w;
  }
  *(float4*)(out + i) = r;
}

// ---------------------------------------------------------------------------
// qgemm: grid (112, 8), 4 waves/block, barrier-free (no LDS).
// Wave = 32 output cols x 64 rows x 512 k. A read directly from xs (L1/L2-hot,
// fragment-ordered), weights dequanted in-register to f16 pairs.
template <bool ATOMIC>
__global__ __launch_bounds__(256, 4) void qgemm_kernel(
    const u32* __restrict__ qw, const u32* __restrict__ qz,
    const float* __restrict__ scal, const u16* __restrict__ xs,
    float* __restrict__ dst) {
  const int tid = threadIdx.x;
  const int lane = tid & 63;
  const int wv = tid >> 6;
  const int g = lane >> 5;                 // k-half within 16k step
  const int nn = lane & 31;
  const int colabs = blockIdx.x * 128 + wv * 32 + nn;
  const int by = blockIdx.y;
  const int r0 = by * 64 + g;              // first qw row == first xs chunk
  const int grp0 = by * 4;                 // first quant group (4 per block)
  const int zsh = (colabs & 7) * 4;

  const u16* pa = xs + ((size_t)r0 * 64 + nn) * 8;     // +1024 elems per step
  const u32* pq = qw + (size_t)r0 * OUT_N + colabs;    // +2*OUT_N per step

  f32x16 acc0, acc1;
#pragma unroll
  for (int i = 0; i < 16; ++i) { acc0[i] = 0.f; acc1[i] = 0.f; }

  // step-0 / group-0 prefetch
  half8 a0 = *(const half8*)pa;
  half8 a1 = *(const half8*)(pa + 256);
  u32 q = *pq;
  float sc_c = scal[(size_t)grp0 * OUT_N + colabs];
  u32 zw_c = qz[(size_t)grp0 * (OUT_N / 8) + (colabs >> 3)];

#pragma unroll
  for (int grp = 0; grp < 4; ++grp) {
    // dequant constants for this group (GROUP=128 == 8 k-steps)
    const u32 zq = (zw_c >> zsh) & 0xFu;
    const u32 hzu = 0x64016401u + zq * 0x00010001u;    // f16x2 of (1025+z)
    half2v hz; __builtin_memcpy(&hz, &hzu, 4);
    const _Float16 hs = (_Float16)sc_c;
    const half2v s2 = {hs, hs};
    if (grp < 3) {                                     // prefetch next group consts
      sc_c = scal[(size_t)(grp0 + grp + 1) * OUT_N + colabs];
      zw_c = qz[(size_t)(grp0 + grp + 1) * (OUT_N / 8) + (colabs >> 3)];
    }
#pragma unroll
    for (int s = 0; s < 8; ++s) {
      const int t = grp * 8 + s;
      half8 a0n = {}, a1n = {};
      u32 qn = 0;
      if (t < 31) {                                    // rolling depth-1 prefetch
        const u16* pan = pa + (size_t)(t + 1) * 1024;
        a0n = *(const half8*)pan;
        a1n = *(const half8*)(pan + 256);
        qn = pq[(size_t)(t + 1) * 2 * OUT_N];
      }
      const u32 p0 = (q & 0x000F000Fu) | 0x64006400u;          // (n0,n4)+1024
      const u32 p1 = ((q >> 4) & 0x000F000Fu) | 0x64006400u;   // (n1,n5)+1024
      const u32 p2 = ((q >> 8) & 0x000F000Fu) | 0x64006400u;   // (n2,n6)+1024
      const u32 p3 = ((q >> 12) & 0x000F000Fu) | 0x64006400u;  // (n3,n7)+1024
      half2v t0, t1, t2, t3;
      __builtin_memcpy(&t0, &p0, 4);
      __builtin_memcpy(&t1, &p1, 4);
      __builtin_memcpy(&t2, &p2, 4);
      __builtin_memcpy(&t3, &p3, 4);
      union { half8 v; half2v h[4]; } bb;
      bb.h[0] = (t0 - hz) * s2;    // exact int sub, then scale (v_pk_*_f16)
      bb.h[1] = (t1 - hz) * s2;
      bb.h[2] = (t2 - hz) * s2;
      bb.h[3] = (t3 - hz) * s2;
      acc0 = __builtin_amdgcn_mfma_f32_32x32x16_f16(a0, bb.v, acc0, 0, 0, 0);
      acc1 = __builtin_amdgcn_mfma_f32_32x32x16_f16(a1, bb.v, acc1, 0, 0, 0);
      a0 = a0n; a1 = a1n; q = qn;
    }
  }

  // C/D layout: col = lane&31, row = (r&3) + 8*(r>>2) + 4*(lane>>5)
#pragma unroll
  for (int r = 0; r < 16; ++r) {
    const int row = (r & 3) + 8 * (r >> 2) + 4 * g;
    if (ATOMIC) {
      unsafeAtomicAdd(&dst[(size_t)row * OUT_N + colabs], acc0[r]);
      unsafeAtomicAdd(&dst[(size_t)(row + 32) * OUT_N + colabs], acc1[r]);
    } else {
      float* p = dst + (size_t)by * OUT_ELEMS;
      p[(size_t)row * OUT_N + colabs] = acc0[r];
      p[(size_t)(row + 32) * OUT_N + colabs] = acc1[r];
    }
  }
}

// ---------------------------------------------------------------------------
extern "C" void kernel_launch(void* const* d_in, const int* in_sizes, int n_in,
                              void* d_out, int out_size, void* d_ws, size_t ws_size,
                              hipStream_t stream) {
  (void)in_sizes; (void)n_in; (void)out_size;
  const float* x    = (const float*)d_in[0];
  const u32*   qw   = (const u32*)d_in[1];
  const u32*   qz   = (const u32*)d_in[2];
  const float* sc   = (const float*)d_in[3];
  const float* bias = (const float*)d_in[4];
  // d_in[5] = g_idx: sequential k/128 for this problem; folded into indexing.
  float* out = (float*)d_out;

  const size_t XS_BYTES   = (size_t)64 * IN_K * 2;              // 512 KB
  const size_t PART_BYTES = (size_t)SPLITK * OUT_ELEMS * 4;     // 29.36 MB
  u16* xs = (u16*)d_ws;

  prep_kernel<<<128, 256, 0, stream>>>(x, xs);

  if (ws_size >= XS_BYTES + PART_BYTES) {
    float* part = (float*)((char*)d_ws + XS_BYTES);
    qgemm_kernel<false><<<dim3(112, SPLITK), 256, 0, stream>>>(qw, qz, sc, xs, part);
    reduce_kernel<<<896, 256, 0, stream>>>(part, bias, out);
  } else {
    bias_init_kernel<<<896, 256, 0, stream>>>(bias, out);
    qgemm_kernel<true><<<dim3(112, SPLITK), 256, 0, stream>>>(qw, qz, sc, xs, out);
  }
}

// Round 4
// 32.617 us; speedup vs baseline: 1.0258x; 1.0258x over previous
//
#include <hip/hip_runtime.h>
#include <hip/hip_bf16.h>

using u32 = unsigned int;
using u16 = unsigned short;

typedef __attribute__((ext_vector_type(8))) _Float16 half8;
typedef __attribute__((ext_vector_type(2))) _Float16 half2v;
typedef __attribute__((ext_vector_type(16))) float f32x16;
typedef __attribute__((ext_vector_type(4))) u32 u32x4;

#define IN_K   4096
#define OUT_N  14336
#define SPLITK 8
#define NSTAGE 4                 // 4 stages x 128k = 512k per block
#define OUT_ELEMS (64 * OUT_N)   // 917504

// ---------------------------------------------------------------------------
// prep: x f32[64][4096] -> xs f16 in MFMA-fragment order.
// xs layout: [512 chunks][64 rows][8 f16]; chunk c covers k = 8c + perm[j],
// perm = {0,4,1,5,2,6,3,7} (matches pair-dequant element order).
__global__ __launch_bounds__(256) void prep_kernel(const float* __restrict__ x,
                                                   u16* __restrict__ xs) {
  const int t = blockIdx.x * 256 + threadIdx.x;   // 32768 threads
  const int c = t >> 6;        // chunk 0..511
  const int r = t & 63;        // row
  const float* px = x + r * IN_K + c * 8;
  const float4 a = *(const float4*)px;
  const float4 b = *(const float4*)(px + 4);
  const float af[4] = {a.x, a.y, a.z, a.w};
  const float bf[4] = {b.x, b.y, b.z, b.w};
  union { u32x4 v; u32 u[4]; } o;
#pragma unroll
  for (int i = 0; i < 4; ++i) {
    const _Float16 hl = (_Float16)af[i];   // k = 8c + i
    const _Float16 hh = (_Float16)bf[i];   // k = 8c + i + 4
    u16 lo, hi;
    __builtin_memcpy(&lo, &hl, 2);
    __builtin_memcpy(&hi, &hh, 2);
    o.u[i] = (u32)lo | ((u32)hi << 16);
  }
  *(u32x4*)(xs + (size_t)t * 8) = o.v;
}

// ---------------------------------------------------------------------------
__global__ __launch_bounds__(256) void bias_init_kernel(const float* __restrict__ bias,
                                                        float* __restrict__ out) {
  const int i = (blockIdx.x * 256 + threadIdx.x) * 4;
  const int col = i % OUT_N;
  *(float4*)(out + i) = *(const float4*)(bias + col);
}

__global__ __launch_bounds__(256) void reduce_kernel(const float* __restrict__ part,
                                                     const float* __restrict__ bias,
                                                     float* __restrict__ out) {
  const int i = (blockIdx.x * 256 + threadIdx.x) * 4;   // 896 blocks
  const int col = i % OUT_N;
  float4 r = *(const float4*)(bias + col);
#pragma unroll
  for (int p = 0; p < SPLITK; ++p) {
    const float4 a = *(const float4*)(part + (size_t)p * OUT_ELEMS + i);
    r.x += a.x; r.y += a.y; r.z += a.z; r.w += a.w;
  }
  *(float4*)(out + i) = r;
}

// ---------------------------------------------------------------------------
// qgemm: grid (112, 8), 4 waves/block. Wave = 32 cols x 64 rows x 512 k.
// A staged to LDS via global_load_lds (double-buffered, counted vmcnt),
// qweight/scale/zero prefetched 2 stages deep, dequant in-register to f16.
template <bool ATOMIC>
__global__ __launch_bounds__(256, 3) void qgemm_kernel(
    const u32* __restrict__ qw, const u32* __restrict__ qz,
    const float* __restrict__ scal, const u16* __restrict__ xs,
    float* __restrict__ dst) {
  __shared__ u16 lds[2][8192];             // 2 x 16 KB stages
  const int tid = threadIdx.x;
  const int lane = tid & 63;
  const int wv = tid >> 6;
  const int g = lane >> 5;                 // k-half within 16k step
  const int nn = lane & 31;
  const int colabs = blockIdx.x * 128 + wv * 32 + nn;
  const int by = blockIdx.y;
  const int chunk0 = by * 64;              // global 8k-chunk base (== qw row base)
  const int grp0 = by * 4;                 // quant groups handled by this block
  const int zsh = (colabs & 7) * 4;

  f32x16 acc0, acc1;
#pragma unroll
  for (int i = 0; i < 16; ++i) { acc0[i] = 0.f; acc1[i] = 0.f; }

  // A-tile stage: 16 KB contiguous, 4 x 16B per thread  (4 VMEM)
  auto issue = [&](int st) {
    const u16* src = xs + (size_t)(chunk0 + st * 16) * 512;
    u16* dstl = &lds[st & 1][0];
#pragma unroll
    for (int r = 0; r < 4; ++r) {
      const int p = r * 256 + tid;
      __builtin_amdgcn_global_load_lds(
          (const __attribute__((address_space(1))) void*)(src + p * 8),
          (__attribute__((address_space(3))) void*)(dstl + p * 8), 16, 0, 0);
    }
  };
  // qweight + scale + zero for one stage (== one group): exactly 10 VMEM
  auto loadQ = [&](int st, u32* qr, float& sr, u32& zr) {
    const int c = chunk0 + st * 16;
#pragma unroll
    for (int s = 0; s < 8; ++s)
      qr[s] = qw[(size_t)(c + 2 * s + g) * OUT_N + colabs];
    sr = scal[(size_t)(grp0 + st) * OUT_N + colabs];
    zr = qz[(size_t)(grp0 + st) * (OUT_N / 8) + (colabs >> 3)];
  };

  u32 qbuf[2][8]; float sbuf[2]; u32 zbuf[2];
  issue(0);                 // 4 VMEM
  loadQ(0, qbuf[0], sbuf[0], zbuf[0]);   // 10 VMEM
  loadQ(1, qbuf[1], sbuf[1], zbuf[1]);   // 10 VMEM

#pragma unroll
  for (int st = 0; st < NSTAGE; ++st) {
    if (st < NSTAGE - 1) {
      __builtin_amdgcn_s_barrier();                 // buf (st+1)&1 free (WAR)
      asm volatile("" ::: "memory");
      issue(st + 1);                                // +4 VMEM
      if (st < NSTAGE - 2)
        // leave in flight: issue(st+1)=4 + loadQ(st+1)=10  -> 14
        asm volatile("s_waitcnt vmcnt(14)" ::: "memory");
      else
        asm volatile("s_waitcnt vmcnt(4)" ::: "memory");
    } else {
      asm volatile("s_waitcnt vmcnt(0)" ::: "memory");
    }
    __builtin_amdgcn_s_barrier();                   // stage st LDS visible
    asm volatile("" ::: "memory");

    // snapshot current-stage operands; refill the slot 2 stages ahead
    u32 qc[8];
#pragma unroll
    for (int s = 0; s < 8; ++s) qc[s] = qbuf[st & 1][s];
    const float scur = sbuf[st & 1];
    const u32 zcur = zbuf[st & 1];
    if (st < NSTAGE - 2)
      loadQ(st + 2, qbuf[st & 1], sbuf[st & 1], zbuf[st & 1]);  // 10 VMEM

    // dequant constants for this group (GROUP = 128 k = 1 stage)
    const u32 zq = (zcur >> zsh) & 0xFu;
    const u32 hzu = 0x64016401u + zq * 0x00010001u;   // f16x2 of (1025+z)
    half2v hz; __builtin_memcpy(&hz, &hzu, 4);
    const _Float16 hs = (_Float16)scur;
    const half2v s2 = {hs, hs};

    const u16* buf = &lds[st & 1][0];
    __builtin_amdgcn_s_setprio(1);
#pragma unroll
    for (int s = 0; s < 8; ++s) {
      const int cl = s * 2 + g;
      const half8 a0 = *(const half8*)(buf + (cl * 64 + nn) * 8);
      const half8 a1 = *(const half8*)(buf + (cl * 64 + nn + 32) * 8);
      const u32 q = qc[s];
      const u32 p0 = (q & 0x000F000Fu) | 0x64006400u;          // (n0,n4)+1024
      const u32 p1 = ((q >> 4) & 0x000F000Fu) | 0x64006400u;   // (n1,n5)+1024
      const u32 p2 = ((q >> 8) & 0x000F000Fu) | 0x64006400u;   // (n2,n6)+1024
      const u32 p3 = ((q >> 12) & 0x000F000Fu) | 0x64006400u;  // (n3,n7)+1024
      half2v t0, t1, t2, t3;
      __builtin_memcpy(&t0, &p0, 4);
      __builtin_memcpy(&t1, &p1, 4);
      __builtin_memcpy(&t2, &p2, 4);
      __builtin_memcpy(&t3, &p3, 4);
      union { half8 v; half2v h[4]; } bb;
      bb.h[0] = (t0 - hz) * s2;    // exact int sub, then scale (v_pk_*_f16)
      bb.h[1] = (t1 - hz) * s2;
      bb.h[2] = (t2 - hz) * s2;
      bb.h[3] = (t3 - hz) * s2;
      acc0 = __builtin_amdgcn_mfma_f32_32x32x16_f16(a0, bb.v, acc0, 0, 0, 0);
      acc1 = __builtin_amdgcn_mfma_f32_32x32x16_f16(a1, bb.v, acc1, 0, 0, 0);
    }
    __builtin_amdgcn_s_setprio(0);
  }

  // C/D layout: col = lane&31, row = (r&3) + 8*(r>>2) + 4*(lane>>5)
#pragma unroll
  for (int r = 0; r < 16; ++r) {
    const int row = (r & 3) + 8 * (r >> 2) + 4 * g;
    if (ATOMIC) {
      unsafeAtomicAdd(&dst[(size_t)row * OUT_N + colabs], acc0[r]);
      unsafeAtomicAdd(&dst[(size_t)(row + 32) * OUT_N + colabs], acc1[r]);
    } else {
      float* p = dst + (size_t)by * OUT_ELEMS;
      p[(size_t)row * OUT_N + colabs] = acc0[r];
      p[(size_t)(row + 32) * OUT_N + colabs] = acc1[r];
    }
  }
}

// ---------------------------------------------------------------------------
extern "C" void kernel_launch(void* const* d_in, const int* in_sizes, int n_in,
                              void* d_out, int out_size, void* d_ws, size_t ws_size,
                              hipStream_t stream) {
  (void)in_sizes; (void)n_in; (void)out_size;
  const float* x    = (const float*)d_in[0];
  const u32*   qw   = (const u32*)d_in[1];
  const u32*   qz   = (const u32*)d_in[2];
  const float* sc   = (const float*)d_in[3];
  const float* bias = (const float*)d_in[4];
  // d_in[5] = g_idx: sequential k/128 for this problem; folded into indexing.
  float* out = (float*)d_out;

  const size_t XS_BYTES   = (size_t)64 * IN_K * 2;              // 512 KB
  const size_t PART_BYTES = (size_t)SPLITK * OUT_ELEMS * 4;     // 29.36 MB
  u16* xs = (u16*)d_ws;

  prep_kernel<<<128, 256, 0, stream>>>(x, xs);

  if (ws_size >= XS_BYTES + PART_BYTES) {
    float* part = (float*)((char*)d_ws + XS_BYTES);
    qgemm_kernel<false><<<dim3(112, SPLITK), 256, 0, stream>>>(qw, qz, sc, xs, part);
    reduce_kernel<<<896, 256, 0, stream>>>(part, bias, out);
  } else {
    bias_init_kernel<<<896, 256, 0, stream>>>(bias, out);
    qgemm_kernel<true><<<dim3(112, SPLITK), 256, 0, stream>>>(qw, qz, sc, xs, out);
  }
}